// Round 9
// baseline (511.012 us; speedup 1.0000x reference)
//
#include <hip/hip_runtime.h>

#define S_LEN 2048
#define DMODEL 1024
#define NHEAD 8
#define DHEAD 128
#define DFF_N 2048
#define BROWS 8192   // B * S

typedef unsigned short u16;
typedef __attribute__((ext_vector_type(8))) short bf16x8;
typedef __attribute__((ext_vector_type(4))) float f32x4;
typedef __attribute__((ext_vector_type(16))) float f32x16;

__device__ __forceinline__ u16 f2bf(float f) {
    union { float f; unsigned int u; } v; v.f = f;
    unsigned int u = v.u;
    unsigned int r = (u + 0x7FFFu + ((u >> 16) & 1u)) >> 16;
    return (u16)r;
}

__device__ __forceinline__ void async_copy16(const u16* g, u16* l) {
    __builtin_amdgcn_global_load_lds((const __attribute__((address_space(1))) void*)g,
                                     (__attribute__((address_space(3))) void*)l, 16, 0, 0);
}

union Frag { bf16x8 v; unsigned u[4]; };

__device__ __forceinline__ unsigned cvt_pk_bf16(float a, float b) {
    unsigned d;
    asm("v_cvt_pk_bf16_f32 %0, %1, %2" : "=v"(d) : "v"(a), "v"(b));
    return d;  // lo = bf16(a), hi = bf16(b)
}

// swaps hi32 lanes of a with lo32 lanes of b (gfx950)
__device__ __forceinline__ void pl32swap(unsigned& a, unsigned& b) {
    asm("v_permlane32_swap_b32 %0, %1" : "+v"(a), "+v"(b));
}

// ---------------- fused convert f32 -> bf16 for q,k,v ----------------
__global__ __launch_bounds__(256) void convert3_kernel(const float* __restrict__ a,
                                                       const float* __restrict__ b,
                                                       const float* __restrict__ c,
                                                       u16* __restrict__ oa,
                                                       u16* __restrict__ ob,
                                                       u16* __restrict__ oc, int n4) {
    const float* src = (blockIdx.y == 0) ? a : (blockIdx.y == 1) ? b : c;
    u16* dst = (blockIdx.y == 0) ? oa : (blockIdx.y == 1) ? ob : oc;
    int i = blockIdx.x * 256 + threadIdx.x;
    if (i < n4) {
        float4 v = ((const float4*)src)[i];
        uint2 o;
        o.x = (unsigned)f2bf(v.x) | ((unsigned)f2bf(v.y) << 16);
        o.y = (unsigned)f2bf(v.z) | ((unsigned)f2bf(v.w) << 16);
        ((uint2*)dst)[i] = o;
    }
}

// ---- tiled transpose + convert: out[b][c][r] = in[b][r][c], coalesced ----
__global__ __launch_bounds__(256) void transpose_bf_tiled(const float* __restrict__ in,
                                                          u16* __restrict__ out,
                                                          int R, int C) {
    __shared__ float T[32][33];
    const long bo = (long)blockIdx.z * R * C;
    const int r0 = blockIdx.y * 32, c0 = blockIdx.x * 32;
    const int tx = threadIdx.x & 31, ty = threadIdx.x >> 5;  // ty 0..7
    for (int k = 0; k < 4; k++)
        T[ty + 8 * k][tx] = in[bo + (long)(r0 + ty + 8 * k) * C + c0 + tx];
    __syncthreads();
    for (int k = 0; k < 4; k++)
        out[bo + (long)(c0 + ty + 8 * k) * R + r0 + tx] = f2bf(T[tx][ty + 8 * k]);
}

// ---- batched transpose for the three (8,1024,128) QKV weights ----
__global__ __launch_bounds__(256) void transpose_qkv_w(const float* __restrict__ Wq,
                                                       const float* __restrict__ Wk,
                                                       const float* __restrict__ Wv,
                                                       u16* __restrict__ WqT,
                                                       u16* __restrict__ WkT,
                                                       u16* __restrict__ WvT) {
    __shared__ float T[32][33];
    const int w = blockIdx.z >> 3, bz = blockIdx.z & 7;
    const float* in = (w == 0) ? Wq : (w == 1) ? Wk : Wv;
    u16* out = (w == 0) ? WqT : (w == 1) ? WkT : WvT;
    const long bo = (long)bz * 1024 * 128;
    const int r0 = blockIdx.y * 32, c0 = blockIdx.x * 32;
    const int tx = threadIdx.x & 31, ty = threadIdx.x >> 5;
    for (int k = 0; k < 4; k++)
        T[ty + 8 * k][tx] = in[bo + (long)(r0 + ty + 8 * k) * 128 + c0 + tx];
    __syncthreads();
    for (int k = 0; k < 4; k++)
        out[bo + (long)(c0 + ty + 8 * k) * 1024 + r0 + tx] = f2bf(T[tx][ty + 8 * k]);
}

// -------- shared GEMM main loop: async LDS double-buffer, 1 barrier/iter --------
__device__ __forceinline__ void gemm_core(const u16* __restrict__ A,
                                          const u16* __restrict__ Bt, int K,
                                          long row0, long col0, u16* As, u16* Bs,
                                          f32x4 (*acc)[4]) {
    const int tid = threadIdx.x;
    const int lane = tid & 63, wave = tid >> 6;
    const int l15 = lane & 15, quad = lane >> 4;
    const int wx = wave & 1, wy = wave >> 1;
    const int srow = wave * 16 + (lane >> 2);
    const int scol = (lane & 3) * 8;
    const u16* ag0 = &A[(row0 + srow) * K + scol];
    const u16* ag1 = &A[(row0 + 64 + srow) * K + scol];
    const u16* bg0 = &Bt[(col0 + srow) * K + scol];
    const u16* bg1 = &Bt[(col0 + 64 + srow) * K + scol];
    const int l0 = (wave * 16) * 32;
    const int l1 = (64 + wave * 16) * 32;
    const int BUF = 128 * 32;

    async_copy16(ag0, &As[l0]);
    async_copy16(ag1, &As[l1]);
    async_copy16(bg0, &Bs[l0]);
    async_copy16(bg1, &Bs[l1]);
    __syncthreads();

    const int nk = K >> 5;
    for (int kt = 0; kt < nk; kt++) {
        const int cur = (kt & 1) * BUF;
        const int nxt = BUF - cur;
        if (kt + 1 < nk) {
            const int k0 = (kt + 1) * 32;
            async_copy16(ag0 + k0, &As[nxt + l0]);
            async_copy16(ag1 + k0, &As[nxt + l1]);
            async_copy16(bg0 + k0, &Bs[nxt + l0]);
            async_copy16(bg1 + k0, &Bs[nxt + l1]);
        }
        bf16x8 af[4], bfr[4];
        for (int mi = 0; mi < 4; mi++)
            af[mi] = *(const bf16x8*)&As[cur + (wy * 64 + mi * 16 + l15) * 32 + quad * 8];
        for (int ni = 0; ni < 4; ni++)
            bfr[ni] = *(const bf16x8*)&Bs[cur + (wx * 64 + ni * 16 + l15) * 32 + quad * 8];
        for (int mi = 0; mi < 4; mi++)
            for (int ni = 0; ni < 4; ni++)
                acc[mi][ni] = __builtin_amdgcn_mfma_f32_16x16x32_bf16(af[mi], bfr[ni],
                                                                      acc[mi][ni], 0, 0, 0);
        __syncthreads();
    }
}

// XCD band swizzle: bijective for nwg % 8 == 0 (all our grids). Each XCD gets a
// contiguous flat band -> its B col-panels stay resident in the XCD-private L2.
__device__ __forceinline__ void xcd_swizzle(long& row0, long& col0) {
    const int gx = gridDim.x;
    const int nwg = gx * gridDim.y;
    const int flat = blockIdx.y * gx + blockIdx.x;
    const int cpx = nwg >> 3;
    const int swz = (flat & 7) * cpx + (flat >> 3);
    row0 = (long)(swz % gx) * 128;
    col0 = (long)(swz / gx) * 128;
}

// ---------------- GEMM: C[M x N] = A[M x K] @ Bt[N x K]^T ----------------
// EPI: 0 = f32 out; 1 = bf16 out; 2 = bias+relu, bf16 out; 3 = bias, f32 out
template <int EPI>
__global__ __launch_bounds__(256) void gemm_bt_kernel(const u16* __restrict__ A,
                                                      const u16* __restrict__ Bt,
                                                      const float* __restrict__ bias,
                                                      void* __restrict__ Cp,
                                                      int N, int K) {
    __shared__ u16 As[2 * 128 * 32];
    __shared__ u16 Bs[2 * 128 * 32];
    const int tid = threadIdx.x;
    const int lane = tid & 63, wave = tid >> 6;
    const int l15 = lane & 15, quad = lane >> 4;
    const int wx = wave & 1, wy = wave >> 1;
    long row0, col0;
    xcd_swizzle(row0, col0);

    f32x4 acc[4][4];
    for (int i = 0; i < 4; i++)
        for (int j = 0; j < 4; j++) acc[i][j] = (f32x4){0.f, 0.f, 0.f, 0.f};

    gemm_core(A, Bt, K, row0, col0, As, Bs, acc);

    for (int mi = 0; mi < 4; mi++)
        for (int ni = 0; ni < 4; ni++) {
            const long col = col0 + wx * 64 + ni * 16 + l15;
            float bv = (EPI == 2 || EPI == 3) ? bias[col] : 0.0f;
            for (int r = 0; r < 4; r++) {
                const long row = row0 + wy * 64 + mi * 16 + quad * 4 + r;
                float v = acc[mi][ni][r] + bv;
                if (EPI == 2) v = fmaxf(v, 0.0f);
                if (EPI == 0 || EPI == 3)
                    ((float*)Cp)[row * N + col] = v;
                else
                    ((u16*)Cp)[row * N + col] = f2bf(v);
            }
        }
}

// ---- batched QKV GEMM: z selects (A, Bt, epilogue); N=K=1024 ----
__global__ __launch_bounds__(256) void gemm_qkv_kernel(const u16* __restrict__ A0,
                                                       const u16* __restrict__ A1,
                                                       const u16* __restrict__ A2,
                                                       const u16* __restrict__ B0,
                                                       const u16* __restrict__ B1,
                                                       const u16* __restrict__ B2,
                                                       u16* __restrict__ Qp,
                                                       u16* __restrict__ Kp,
                                                       u16* __restrict__ Vtp) {
    __shared__ u16 As[2 * 128 * 32];
    __shared__ u16 Bs[2 * 128 * 32];
    const int z = blockIdx.z;
    const u16* A = (z == 0) ? A0 : (z == 1) ? A1 : A2;
    const u16* Bt = (z == 0) ? B0 : (z == 1) ? B1 : B2;
    const int tid = threadIdx.x;
    const int lane = tid & 63, wave = tid >> 6;
    const int l15 = lane & 15, quad = lane >> 4;
    const int wx = wave & 1, wy = wave >> 1;
    long row0, col0;
    xcd_swizzle(row0, col0);

    f32x4 acc[4][4];
    for (int i = 0; i < 4; i++)
        for (int j = 0; j < 4; j++) acc[i][j] = (f32x4){0.f, 0.f, 0.f, 0.f};

    gemm_core(A, Bt, 1024, row0, col0, As, Bs, acc);

    if (z == 2) {
        // transposed bf16 store: Vt[((b*8+h)*128+dv)*2048 + s]
        for (int mi = 0; mi < 4; mi++)
            for (int ni = 0; ni < 4; ni++) {
                const int row = (int)row0 + wy * 64 + mi * 16 + quad * 4;  // = b*2048 + s
                const int col = (int)col0 + wx * 64 + ni * 16 + l15;       // = h*128 + dv
                const int bb = row >> 11, s = row & 2047;
                uint2 o;
                o.x = (unsigned)f2bf(acc[mi][ni][0]) | ((unsigned)f2bf(acc[mi][ni][1]) << 16);
                o.y = (unsigned)f2bf(acc[mi][ni][2]) | ((unsigned)f2bf(acc[mi][ni][3]) << 16);
                *(uint2*)&Vtp[((long)(bb * 1024 + col) << 11) + s] = o;
            }
    } else {
        u16* Cp = (z == 0) ? Qp : Kp;
        for (int mi = 0; mi < 4; mi++)
            for (int ni = 0; ni < 4; ni++) {
                const long col = col0 + wx * 64 + ni * 16 + l15;
                for (int r = 0; r < 4; r++) {
                    const long row = row0 + wy * 64 + mi * 16 + quad * 4 + r;
                    Cp[row * 1024 + col] = f2bf(acc[mi][ni][r]);
                }
            }
    }
}

// ---------------- Flash attention v4: swapped QK^T, in-register softmax ----------------
// vs R7 (verified): (a) mask addend c[s] = fmaf(m,1e30,-1e30)-20 precomputed ONCE
// into an 8 KB LDS table (was: 8 global float4 loads + 64 fma per lane per iter;
// new inner math exp(st + c) is numerically IDENTICAL — fmaf(1,a,b)==a+b);
// (b) lsum split into 8 independent partials (kills a 32-deep serial add chain).
__global__ __launch_bounds__(256, 2) void attn_kernel(const u16* __restrict__ Q,
                                                      const u16* __restrict__ Km,
                                                      const u16* __restrict__ Vt,
                                                      const float* __restrict__ mask,
                                                      u16* __restrict__ O) {
    __shared__ u16 Kb[2][64 * 128];   // [s 0..63][dk, swizzled 16B blocks]
    __shared__ u16 Vb[2][128 * 64];   // [dv 0..127][s, swizzled 16B blocks]
    __shared__ float Mc[S_LEN];       // mask addend table, 8 KB
    const int tid = threadIdx.x;
    const int lane = tid & 63, wave = tid >> 6;
    const int l31 = lane & 31, half = lane >> 5;

    // XCD-aware decode: all 16 q-tiles of a (b,h) share one XCD's L2
    const int linear = blockIdx.x;            // 0..511
    const int xcd = linear & 7, jj = linear >> 3;
    const int bh = xcd * 4 + (jj & 3);        // 4 (b,h) streams per XCD
    const int qt = jj >> 2;                   // 0..15
    const int b = bh >> 3, h = bh & 7;

    const long baseQ = ((long)b * S_LEN) * DMODEL + h * DHEAD;
    const long baseV = ((long)(b * NHEAD + h) * DHEAD) * S_LEN;
    const int q0 = qt * 128 + wave * 32;

    bf16x8 qf[8];
#pragma unroll
    for (int kk = 0; kk < 8; kk++)
        qf[kk] = *(const bf16x8*)&Q[baseQ + (long)(q0 + l31) * DMODEL + kk * 16 + half * 8];

    // staging descriptors: K 16 instrs/tile (4/wave), V 16 instrs/tile (4/wave)
    const int krow = 4 * wave + (lane >> 4);            // j adds 16 rows
    const int kcb = (lane & 15) ^ (krow & 7);
    const u16* gK = Km + baseQ + (long)krow * DMODEL + kcb * 8;
    const int vrow = 8 * wave + (lane >> 3);            // j adds 32 rows
    const int vcb = (lane & 7) ^ (vrow & 7);
    const u16* gV = Vt + baseV + (long)vrow * S_LEN + vcb * 8;
    const int ldo = wave * 512;                         // u16; + j*2048

    f32x16 oacc[4];
#pragma unroll
    for (int i = 0; i < 4; i++)
#pragma unroll
        for (int r = 0; r < 16; r++) oacc[i][r] = 0.f;
    float ls[8];
#pragma unroll
    for (int i = 0; i < 8; i++) ls[i] = 0.f;

    // prologue: mask addend table + stage tile 0 into buffer 0
#pragma unroll
    for (int i = 0; i < S_LEN / 256; i++) {
        const float m = mask[(long)b * S_LEN + i * 256 + tid];
        Mc[i * 256 + tid] = fmaf(m, 1e30f, -1e30f) - 20.0f;
    }
#pragma unroll
    for (int j = 0; j < 4; j++) {
        async_copy16(gK + j * (16 * DMODEL), &Kb[0][ldo + j * 2048]);
        async_copy16(gV + j * (32 * S_LEN), &Vb[0][ldo + j * 2048]);
    }
    __syncthreads();

    const int NT = S_LEN / 64;
    for (int kt = 0; kt < NT; kt++) {
        const int cur = kt & 1, nxt = cur ^ 1;
        if (kt + 1 < NT) {
            const long koff = (long)(kt + 1) * 64 * DMODEL;
            const long voff = (long)(kt + 1) * 64;
#pragma unroll
            for (int j = 0; j < 4; j++) {
                async_copy16(gK + koff + j * (16 * DMODEL), &Kb[nxt][ldo + j * 2048]);
                async_copy16(gV + voff + j * (32 * S_LEN), &Vb[nxt][ldo + j * 2048]);
            }
        }
        const float4* mc = (const float4*)&Mc[kt * 64];

        // QK^T swapped: A = K rows (s), B = Q cols (q) -> P lane-local per q row
        f32x16 st0, st1;
#pragma unroll
        for (int r = 0; r < 16; r++) { st0[r] = 0.f; st1[r] = 0.f; }
#pragma unroll
        for (int kk = 0; kk < 8; kk++) {
            const int cb = ((kk * 2 + half) ^ (l31 & 7)) * 8;
            bf16x8 kf0 = *(const bf16x8*)&Kb[cur][l31 * 128 + cb];
            bf16x8 kf1 = *(const bf16x8*)&Kb[cur][(32 + l31) * 128 + cb];
            st0 = __builtin_amdgcn_mfma_f32_32x32x16_bf16(kf0, qf[kk], st0, 0, 0, 0);
            st1 = __builtin_amdgcn_mfma_f32_32x32x16_bf16(kf1, qf[kk], st1, 0, 0, 0);
        }

        // p = exp(st + c[s]); pack to bf16 dwords per 4-row group
        unsigned dw[8][2];
#pragma unroll
        for (int g = 0; g < 4; g++) {
            const float4 c0 = mc[2 * g + half];        // s = 8g + 4*half + 0..3
            const float4 c1 = mc[8 + 2 * g + half];    // + 32
            const float cv0[4] = {c0.x, c0.y, c0.z, c0.w};
            const float cv1[4] = {c1.x, c1.y, c1.z, c1.w};
            float p0[4], p1[4];
#pragma unroll
            for (int jl = 0; jl < 4; jl++) {
                const int r = 4 * g + jl;
                p0[jl] = __expf(st0[r] + cv0[jl]);
                p1[jl] = __expf(st1[r] + cv1[jl]);
            }
            ls[g]     += (p0[0] + p0[1]) + (p0[2] + p0[3]);
            ls[4 + g] += (p1[0] + p1[1]) + (p1[2] + p1[3]);
            dw[g][0] = cvt_pk_bf16(p0[0], p0[1]);
            dw[g][1] = cvt_pk_bf16(p0[2], p0[3]);
            dw[4 + g][0] = cvt_pk_bf16(p1[0], p1[1]);
            dw[4 + g][1] = cvt_pk_bf16(p1[2], p1[3]);
        }
        // permlane32_swap: frag f (s-chunk 16f..16f+15), word t from h'=0, word 2+t from h'=1
        Frag pa[4];
#pragma unroll
        for (int f = 0; f < 4; f++)
#pragma unroll
            for (int t = 0; t < 2; t++) {
                unsigned a = dw[2 * f][t], bq = dw[2 * f + 1][t];
                pl32swap(a, bq);
                pa[f].u[t] = a;
                pa[f].u[2 + t] = bq;
            }
        // PV: 4 s-chunks x 4 dv-blocks
#pragma unroll
        for (int f = 0; f < 4; f++)
#pragma unroll
            for (int nt = 0; nt < 4; nt++) {
                bf16x8 vf = *(const bf16x8*)&Vb[cur][(nt * 32 + l31) * 64 +
                                                     (((2 * f + half) ^ (l31 & 7)) * 8)];
                oacc[nt] = __builtin_amdgcn_mfma_f32_32x32x16_bf16(pa[f].v, vf, oacc[nt], 0, 0, 0);
            }
        __syncthreads();  // publishes buf[nxt]; prefetch had the whole iter to land
    }

    // denominator: lanes (l31, h) + (l31, h^1) together hold the full row sum
    float lsum = ((ls[0] + ls[1]) + (ls[2] + ls[3])) + ((ls[4] + ls[5]) + (ls[6] + ls[7]));
    lsum += __shfl_xor(lsum, 32, 64);
    const float invq = 1.0f / lsum;            // denom for q = l31
    float invv[16];
#pragma unroll
    for (int r = 0; r < 16; r++)
        invv[r] = __shfl(invq, (r & 3) + 8 * (r >> 2) + 4 * half, 64);
#pragma unroll
    for (int nt = 0; nt < 4; nt++)
#pragma unroll
        for (int r = 0; r < 16; r++) {
            const int row = (r & 3) + 8 * (r >> 2) + 4 * half;
            O[baseQ + (long)(q0 + row) * DMODEL + nt * 32 + l31] = f2bf(oacc[nt][r] * invv[r]);
        }
}

// ------------- residual + layernorm: out = LN(a + b) * g + be -------------
__global__ __launch_bounds__(256) void ln_kernel(const float* __restrict__ a,
                                                 const float* __restrict__ b,
                                                 const float* __restrict__ gamma,
                                                 const float* __restrict__ beta, int gi,
                                                 float* __restrict__ out_f,
                                                 u16* __restrict__ out_bf) {
    __shared__ float red[8];
    const int row = blockIdx.x;
    const int tid = threadIdx.x;
    const long off = (long)row * DMODEL + tid * 4;
    float4 va = *(const float4*)&a[off];
    float4 vb = *(const float4*)&b[off];
    float4 v;
    v.x = va.x + vb.x; v.y = va.y + vb.y; v.z = va.z + vb.z; v.w = va.w + vb.w;
    float s = v.x + v.y + v.z + v.w;
    float sq = v.x * v.x + v.y * v.y + v.z * v.z + v.w * v.w;
    for (int d = 1; d < 64; d <<= 1) {
        s += __shfl_xor(s, d, 64);
        sq += __shfl_xor(sq, d, 64);
    }
    int wave = tid >> 6;
    if ((tid & 63) == 0) { red[wave * 2] = s; red[wave * 2 + 1] = sq; }
    __syncthreads();
    s = red[0] + red[2] + red[4] + red[6];
    sq = red[1] + red[3] + red[5] + red[7];
    float mean = s * (1.0f / DMODEL);
    float var = sq * (1.0f / DMODEL) - mean * mean;
    float rstd = rsqrtf(var + 1e-14f);
    float g = gamma[gi], be = beta[gi];
    float4 o;
    o.x = (v.x - mean) * rstd * g + be;
    o.y = (v.y - mean) * rstd * g + be;
    o.z = (v.z - mean) * rstd * g + be;
    o.w = (v.w - mean) * rstd * g + be;
    *(float4*)&out_f[off] = o;
    if (out_bf) {
        uint2 ob;
        ob.x = (unsigned)f2bf(o.x) | ((unsigned)f2bf(o.y) << 16);
        ob.y = (unsigned)f2bf(o.z) | ((unsigned)f2bf(o.w) << 16);
        *(uint2*)&out_bf[off] = ob;
    }
}

extern "C" void kernel_launch(void* const* d_in, const int* in_sizes, int n_in,
                              void* d_out, int out_size, void* d_ws, size_t ws_size,
                              hipStream_t stream) {
    const float* query = (const float*)d_in[0];
    const float* key   = (const float*)d_in[1];
    const float* value = (const float*)d_in[2];
    const float* mask  = (const float*)d_in[3];
    const float* Wq = (const float*)d_in[4];
    const float* Wk = (const float*)d_in[5];
    const float* Wv = (const float*)d_in[6];
    const float* Wo = (const float*)d_in[7];
    const float* W1 = (const float*)d_in[8];
    const float* b1 = (const float*)d_in[9];
    const float* W2 = (const float*)d_in[10];
    const float* b2 = (const float*)d_in[11];
    const float* gamma = (const float*)d_in[12];
    const float* beta  = (const float*)d_in[13];

    char* ws = (char*)d_ws;
    const size_t MB = 1024 * 1024;
    u16* WqT = (u16*)(ws + 0 * MB);    // 2 MB  (H*DK, D)
    u16* WkT = (u16*)(ws + 2 * MB);    // 2 MB
    u16* WvT = (u16*)(ws + 4 * MB);    // 2 MB
    u16* WoT = (u16*)(ws + 6 * MB);    // 2 MB  (D, H*DV)
    u16* W1T = (u16*)(ws + 8 * MB);    // 4 MB  (DFF, D)
    u16* W2T = (u16*)(ws + 12 * MB);   // 4 MB  (D, DFF)
    u16* qbf = (u16*)(ws + 16 * MB);   // 16 MB   (later reused as x_bf)
    u16* kbf = (u16*)(ws + 32 * MB);   // 16 MB   (kbf+vbf later reused as h1, 32 MB)
    u16* vbf = (u16*)(ws + 48 * MB);   // 16 MB
    u16* Qp  = (u16*)(ws + 64 * MB);   // 16 MB
    u16* Kp  = (u16*)(ws + 80 * MB);   // 16 MB
    u16* VtP = (u16*)(ws + 96 * MB);   // 16 MB  Vt[b][h][dv][s]
    u16* Op  = (u16*)(ws + 112 * MB);  // 16 MB
    float* proj = (float*)(ws + 128 * MB);  // 32 MB (later reused as FFN out)
    float* xf   = (float*)(ws + 160 * MB);  // 32 MB
    u16* xbf = qbf;
    u16* h1  = kbf;

    // ---- weight packing (tiled transpose + bf16, coalesced both sides) ----
    transpose_qkv_w<<<dim3(4, 32, 24), 256, 0, stream>>>(Wq, Wk, Wv, WqT, WkT, WvT);
    transpose_bf_tiled<<<dim3(32, 32, 1), 256, 0, stream>>>(Wo, WoT, 1024, 1024);
    transpose_bf_tiled<<<dim3(64, 32, 1), 256, 0, stream>>>(W1, W1T, 1024, 2048);
    transpose_bf_tiled<<<dim3(32, 64, 1), 256, 0, stream>>>(W2, W2T, 2048, 1024);

    // ---- activation conversion (fused q,k,v) ----
    const int n4 = BROWS * DMODEL / 4;
    convert3_kernel<<<dim3(n4 / 256, 3), 256, 0, stream>>>(query, key, value, qbf, kbf, vbf, n4);

    // ---- QKV projections, one batched launch (z=0:Q, 1:K, 2:V->transposed) ----
    gemm_qkv_kernel<<<dim3(64, 8, 3), 256, 0, stream>>>(qbf, kbf, vbf, WqT, WkT, WvT,
                                                        Qp, Kp, VtP);

    // ---- attention (512 blocks, XCD-swizzled decode inside) ----
    attn_kernel<<<dim3(512, 1, 1), 256, 0, stream>>>(Qp, Kp, VtP, mask, Op);

    // ---- output projection ----
    gemm_bt_kernel<0><<<dim3(64, 8), 256, 0, stream>>>(Op, WoT, nullptr, proj, 1024, 1024);

    // ---- LN1: x = LN(value + proj) ----
    ln_kernel<<<dim3(BROWS), 256, 0, stream>>>(value, proj, gamma, beta, 0, xf, xbf);

    // ---- FFN ----
    gemm_bt_kernel<2><<<dim3(64, 16), 256, 0, stream>>>(xbf, W1T, b1, h1, 2048, 1024);
    gemm_bt_kernel<3><<<dim3(64, 8), 256, 0, stream>>>(h1, W2T, b2, proj, 1024, 2048);

    // ---- LN2: out = LN(x + ffn) ----
    ln_kernel<<<dim3(BROWS), 256, 0, stream>>>(xf, proj, gamma, beta, 1, (float*)d_out, nullptr);
}

// Round 10
// 499.849 us; speedup vs baseline: 1.0223x; 1.0223x over previous
//
#include <hip/hip_runtime.h>

#define S_LEN 2048
#define DMODEL 1024
#define NHEAD 8
#define DHEAD 128
#define DFF_N 2048
#define BROWS 8192   // B * S

typedef unsigned short u16;
typedef __attribute__((ext_vector_type(8))) short bf16x8;
typedef __attribute__((ext_vector_type(4))) float f32x4;
typedef __attribute__((ext_vector_type(16))) float f32x16;

__device__ __forceinline__ u16 f2bf(float f) {
    union { float f; unsigned int u; } v; v.f = f;
    unsigned int u = v.u;
    unsigned int r = (u + 0x7FFFu + ((u >> 16) & 1u)) >> 16;
    return (u16)r;
}

__device__ __forceinline__ void async_copy16(const u16* g, u16* l) {
    __builtin_amdgcn_global_load_lds((const __attribute__((address_space(1))) void*)g,
                                     (__attribute__((address_space(3))) void*)l, 16, 0, 0);
}

union Frag { bf16x8 v; unsigned u[4]; };

__device__ __forceinline__ unsigned cvt_pk_bf16(float a, float b) {
    unsigned d;
    asm("v_cvt_pk_bf16_f32 %0, %1, %2" : "=v"(d) : "v"(a), "v"(b));
    return d;  // lo = bf16(a), hi = bf16(b)
}

// swaps hi32 lanes of a with lo32 lanes of b (gfx950)
__device__ __forceinline__ void pl32swap(unsigned& a, unsigned& b) {
    asm("v_permlane32_swap_b32 %0, %1" : "+v"(a), "+v"(b));
}

// ---------------- fused convert f32 -> bf16 for q,k,v ----------------
__global__ __launch_bounds__(256) void convert3_kernel(const float* __restrict__ a,
                                                       const float* __restrict__ b,
                                                       const float* __restrict__ c,
                                                       u16* __restrict__ oa,
                                                       u16* __restrict__ ob,
                                                       u16* __restrict__ oc, int n4) {
    const float* src = (blockIdx.y == 0) ? a : (blockIdx.y == 1) ? b : c;
    u16* dst = (blockIdx.y == 0) ? oa : (blockIdx.y == 1) ? ob : oc;
    int i = blockIdx.x * 256 + threadIdx.x;
    if (i < n4) {
        float4 v = ((const float4*)src)[i];
        uint2 o;
        o.x = (unsigned)f2bf(v.x) | ((unsigned)f2bf(v.y) << 16);
        o.y = (unsigned)f2bf(v.z) | ((unsigned)f2bf(v.w) << 16);
        ((uint2*)dst)[i] = o;
    }
}

// ---- tiled transpose + convert: out[b][c][r] = in[b][r][c], coalesced ----
__global__ __launch_bounds__(256) void transpose_bf_tiled(const float* __restrict__ in,
                                                          u16* __restrict__ out,
                                                          int R, int C) {
    __shared__ float T[32][33];
    const long bo = (long)blockIdx.z * R * C;
    const int r0 = blockIdx.y * 32, c0 = blockIdx.x * 32;
    const int tx = threadIdx.x & 31, ty = threadIdx.x >> 5;  // ty 0..7
    for (int k = 0; k < 4; k++)
        T[ty + 8 * k][tx] = in[bo + (long)(r0 + ty + 8 * k) * C + c0 + tx];
    __syncthreads();
    for (int k = 0; k < 4; k++)
        out[bo + (long)(c0 + ty + 8 * k) * R + r0 + tx] = f2bf(T[tx][ty + 8 * k]);
}

// ---- batched transpose for the three (8,1024,128) QKV weights ----
__global__ __launch_bounds__(256) void transpose_qkv_w(const float* __restrict__ Wq,
                                                       const float* __restrict__ Wk,
                                                       const float* __restrict__ Wv,
                                                       u16* __restrict__ WqT,
                                                       u16* __restrict__ WkT,
                                                       u16* __restrict__ WvT) {
    __shared__ float T[32][33];
    const int w = blockIdx.z >> 3, bz = blockIdx.z & 7;
    const float* in = (w == 0) ? Wq : (w == 1) ? Wk : Wv;
    u16* out = (w == 0) ? WqT : (w == 1) ? WkT : WvT;
    const long bo = (long)bz * 1024 * 128;
    const int r0 = blockIdx.y * 32, c0 = blockIdx.x * 32;
    const int tx = threadIdx.x & 31, ty = threadIdx.x >> 5;
    for (int k = 0; k < 4; k++)
        T[ty + 8 * k][tx] = in[bo + (long)(r0 + ty + 8 * k) * 128 + c0 + tx];
    __syncthreads();
    for (int k = 0; k < 4; k++)
        out[bo + (long)(c0 + ty + 8 * k) * 1024 + r0 + tx] = f2bf(T[tx][ty + 8 * k]);
}

// -------- shared GEMM main loop: async LDS double-buffer, 1 barrier/iter --------
__device__ __forceinline__ void gemm_core(const u16* __restrict__ A,
                                          const u16* __restrict__ Bt, int K,
                                          long row0, long col0, u16* As, u16* Bs,
                                          f32x4 (*acc)[4]) {
    const int tid = threadIdx.x;
    const int lane = tid & 63, wave = tid >> 6;
    const int l15 = lane & 15, quad = lane >> 4;
    const int wx = wave & 1, wy = wave >> 1;
    const int srow = wave * 16 + (lane >> 2);
    const int scol = (lane & 3) * 8;
    const u16* ag0 = &A[(row0 + srow) * K + scol];
    const u16* ag1 = &A[(row0 + 64 + srow) * K + scol];
    const u16* bg0 = &Bt[(col0 + srow) * K + scol];
    const u16* bg1 = &Bt[(col0 + 64 + srow) * K + scol];
    const int l0 = (wave * 16) * 32;
    const int l1 = (64 + wave * 16) * 32;
    const int BUF = 128 * 32;

    async_copy16(ag0, &As[l0]);
    async_copy16(ag1, &As[l1]);
    async_copy16(bg0, &Bs[l0]);
    async_copy16(bg1, &Bs[l1]);
    __syncthreads();

    const int nk = K >> 5;
    for (int kt = 0; kt < nk; kt++) {
        const int cur = (kt & 1) * BUF;
        const int nxt = BUF - cur;
        if (kt + 1 < nk) {
            const int k0 = (kt + 1) * 32;
            async_copy16(ag0 + k0, &As[nxt + l0]);
            async_copy16(ag1 + k0, &As[nxt + l1]);
            async_copy16(bg0 + k0, &Bs[nxt + l0]);
            async_copy16(bg1 + k0, &Bs[nxt + l1]);
        }
        bf16x8 af[4], bfr[4];
        for (int mi = 0; mi < 4; mi++)
            af[mi] = *(const bf16x8*)&As[cur + (wy * 64 + mi * 16 + l15) * 32 + quad * 8];
        for (int ni = 0; ni < 4; ni++)
            bfr[ni] = *(const bf16x8*)&Bs[cur + (wx * 64 + ni * 16 + l15) * 32 + quad * 8];
        for (int mi = 0; mi < 4; mi++)
            for (int ni = 0; ni < 4; ni++)
                acc[mi][ni] = __builtin_amdgcn_mfma_f32_16x16x32_bf16(af[mi], bfr[ni],
                                                                      acc[mi][ni], 0, 0, 0);
        __syncthreads();
    }
}

// NOTE (R9 lesson): NO XCD swizzle here. For grids with gridDim.x = 64 (all ours),
// the DEFAULT round-robin dispatch already places the 8-16 blocks sharing an
// A-row-panel on the same XCD (64 = 0 mod 8), giving a ~4 MB L2 working set.
// The R9 col-banded swizzle broke this: FETCH_SIZE 54 -> 200 MB on qkv.

// ---------------- GEMM: C[M x N] = A[M x K] @ Bt[N x K]^T ----------------
// EPI: 0 = f32 out; 1 = bf16 out; 2 = bias+relu, bf16 out; 3 = bias, f32 out
template <int EPI>
__global__ __launch_bounds__(256) void gemm_bt_kernel(const u16* __restrict__ A,
                                                      const u16* __restrict__ Bt,
                                                      const float* __restrict__ bias,
                                                      void* __restrict__ Cp,
                                                      int N, int K) {
    __shared__ u16 As[2 * 128 * 32];
    __shared__ u16 Bs[2 * 128 * 32];
    const int tid = threadIdx.x;
    const int lane = tid & 63, wave = tid >> 6;
    const int l15 = lane & 15, quad = lane >> 4;
    const int wx = wave & 1, wy = wave >> 1;
    const long row0 = (long)blockIdx.x * 128;
    const long col0 = (long)blockIdx.y * 128;

    f32x4 acc[4][4];
    for (int i = 0; i < 4; i++)
        for (int j = 0; j < 4; j++) acc[i][j] = (f32x4){0.f, 0.f, 0.f, 0.f};

    gemm_core(A, Bt, K, row0, col0, As, Bs, acc);

    for (int mi = 0; mi < 4; mi++)
        for (int ni = 0; ni < 4; ni++) {
            const long col = col0 + wx * 64 + ni * 16 + l15;
            float bv = (EPI == 2 || EPI == 3) ? bias[col] : 0.0f;
            for (int r = 0; r < 4; r++) {
                const long row = row0 + wy * 64 + mi * 16 + quad * 4 + r;
                float v = acc[mi][ni][r] + bv;
                if (EPI == 2) v = fmaxf(v, 0.0f);
                if (EPI == 0 || EPI == 3)
                    ((float*)Cp)[row * N + col] = v;
                else
                    ((u16*)Cp)[row * N + col] = f2bf(v);
            }
        }
}

// ---- batched QKV GEMM: z selects (A, Bt, epilogue); N=K=1024 ----
__global__ __launch_bounds__(256) void gemm_qkv_kernel(const u16* __restrict__ A0,
                                                       const u16* __restrict__ A1,
                                                       const u16* __restrict__ A2,
                                                       const u16* __restrict__ B0,
                                                       const u16* __restrict__ B1,
                                                       const u16* __restrict__ B2,
                                                       u16* __restrict__ Qp,
                                                       u16* __restrict__ Kp,
                                                       u16* __restrict__ Vtp) {
    __shared__ u16 As[2 * 128 * 32];
    __shared__ u16 Bs[2 * 128 * 32];
    const int z = blockIdx.z;
    const u16* A = (z == 0) ? A0 : (z == 1) ? A1 : A2;
    const u16* Bt = (z == 0) ? B0 : (z == 1) ? B1 : B2;
    const int tid = threadIdx.x;
    const int lane = tid & 63, wave = tid >> 6;
    const int l15 = lane & 15, quad = lane >> 4;
    const int wx = wave & 1, wy = wave >> 1;
    const long row0 = (long)blockIdx.x * 128;
    const long col0 = (long)blockIdx.y * 128;

    f32x4 acc[4][4];
    for (int i = 0; i < 4; i++)
        for (int j = 0; j < 4; j++) acc[i][j] = (f32x4){0.f, 0.f, 0.f, 0.f};

    gemm_core(A, Bt, 1024, row0, col0, As, Bs, acc);

    if (z == 2) {
        // transposed bf16 store: Vt[((b*8+h)*128+dv)*2048 + s]
        for (int mi = 0; mi < 4; mi++)
            for (int ni = 0; ni < 4; ni++) {
                const int row = (int)row0 + wy * 64 + mi * 16 + quad * 4;  // = b*2048 + s
                const int col = (int)col0 + wx * 64 + ni * 16 + l15;       // = h*128 + dv
                const int bb = row >> 11, s = row & 2047;
                uint2 o;
                o.x = (unsigned)f2bf(acc[mi][ni][0]) | ((unsigned)f2bf(acc[mi][ni][1]) << 16);
                o.y = (unsigned)f2bf(acc[mi][ni][2]) | ((unsigned)f2bf(acc[mi][ni][3]) << 16);
                *(uint2*)&Vtp[((long)(bb * 1024 + col) << 11) + s] = o;
            }
    } else {
        u16* Cp = (z == 0) ? Qp : Kp;
        for (int mi = 0; mi < 4; mi++)
            for (int ni = 0; ni < 4; ni++) {
                const long col = col0 + wx * 64 + ni * 16 + l15;
                for (int r = 0; r < 4; r++) {
                    const long row = row0 + wy * 64 + mi * 16 + quad * 4 + r;
                    Cp[row * 1024 + col] = f2bf(acc[mi][ni][r]);
                }
            }
    }
}

// ---------------- Flash attention v4: swapped QK^T, in-register softmax ----------------
// (verified R9: mask addend LDS table + 8-way lsum partials; attn < 89 us)
__global__ __launch_bounds__(256, 2) void attn_kernel(const u16* __restrict__ Q,
                                                      const u16* __restrict__ Km,
                                                      const u16* __restrict__ Vt,
                                                      const float* __restrict__ mask,
                                                      u16* __restrict__ O) {
    __shared__ u16 Kb[2][64 * 128];   // [s 0..63][dk, swizzled 16B blocks]
    __shared__ u16 Vb[2][128 * 64];   // [dv 0..127][s, swizzled 16B blocks]
    __shared__ float Mc[S_LEN];       // mask addend table, 8 KB
    const int tid = threadIdx.x;
    const int lane = tid & 63, wave = tid >> 6;
    const int l31 = lane & 31, half = lane >> 5;

    // XCD-aware decode: all 16 q-tiles of a (b,h) share one XCD's L2
    const int linear = blockIdx.x;            // 0..511
    const int xcd = linear & 7, jj = linear >> 3;
    const int bh = xcd * 4 + (jj & 3);        // 4 (b,h) streams per XCD
    const int qt = jj >> 2;                   // 0..15
    const int b = bh >> 3, h = bh & 7;

    const long baseQ = ((long)b * S_LEN) * DMODEL + h * DHEAD;
    const long baseV = ((long)(b * NHEAD + h) * DHEAD) * S_LEN;
    const int q0 = qt * 128 + wave * 32;

    bf16x8 qf[8];
#pragma unroll
    for (int kk = 0; kk < 8; kk++)
        qf[kk] = *(const bf16x8*)&Q[baseQ + (long)(q0 + l31) * DMODEL + kk * 16 + half * 8];

    // staging descriptors: K 16 instrs/tile (4/wave), V 16 instrs/tile (4/wave)
    const int krow = 4 * wave + (lane >> 4);            // j adds 16 rows
    const int kcb = (lane & 15) ^ (krow & 7);
    const u16* gK = Km + baseQ + (long)krow * DMODEL + kcb * 8;
    const int vrow = 8 * wave + (lane >> 3);            // j adds 32 rows
    const int vcb = (lane & 7) ^ (vrow & 7);
    const u16* gV = Vt + baseV + (long)vrow * S_LEN + vcb * 8;
    const int ldo = wave * 512;                         // u16; + j*2048

    f32x16 oacc[4];
#pragma unroll
    for (int i = 0; i < 4; i++)
#pragma unroll
        for (int r = 0; r < 16; r++) oacc[i][r] = 0.f;
    float ls[8];
#pragma unroll
    for (int i = 0; i < 8; i++) ls[i] = 0.f;

    // prologue: mask addend table + stage tile 0 into buffer 0
#pragma unroll
    for (int i = 0; i < S_LEN / 256; i++) {
        const float m = mask[(long)b * S_LEN + i * 256 + tid];
        Mc[i * 256 + tid] = fmaf(m, 1e30f, -1e30f) - 20.0f;
    }
#pragma unroll
    for (int j = 0; j < 4; j++) {
        async_copy16(gK + j * (16 * DMODEL), &Kb[0][ldo + j * 2048]);
        async_copy16(gV + j * (32 * S_LEN), &Vb[0][ldo + j * 2048]);
    }
    __syncthreads();

    const int NT = S_LEN / 64;
    for (int kt = 0; kt < NT; kt++) {
        const int cur = kt & 1, nxt = cur ^ 1;
        if (kt + 1 < NT) {
            const long koff = (long)(kt + 1) * 64 * DMODEL;
            const long voff = (long)(kt + 1) * 64;
#pragma unroll
            for (int j = 0; j < 4; j++) {
                async_copy16(gK + koff + j * (16 * DMODEL), &Kb[nxt][ldo + j * 2048]);
                async_copy16(gV + voff + j * (32 * S_LEN), &Vb[nxt][ldo + j * 2048]);
            }
        }
        const float4* mc = (const float4*)&Mc[kt * 64];

        // QK^T swapped: A = K rows (s), B = Q cols (q) -> P lane-local per q row
        f32x16 st0, st1;
#pragma unroll
        for (int r = 0; r < 16; r++) { st0[r] = 0.f; st1[r] = 0.f; }
#pragma unroll
        for (int kk = 0; kk < 8; kk++) {
            const int cb = ((kk * 2 + half) ^ (l31 & 7)) * 8;
            bf16x8 kf0 = *(const bf16x8*)&Kb[cur][l31 * 128 + cb];
            bf16x8 kf1 = *(const bf16x8*)&Kb[cur][(32 + l31) * 128 + cb];
            st0 = __builtin_amdgcn_mfma_f32_32x32x16_bf16(kf0, qf[kk], st0, 0, 0, 0);
            st1 = __builtin_amdgcn_mfma_f32_32x32x16_bf16(kf1, qf[kk], st1, 0, 0, 0);
        }

        // p = exp(st + c[s]); pack to bf16 dwords per 4-row group
        unsigned dw[8][2];
#pragma unroll
        for (int g = 0; g < 4; g++) {
            const float4 c0 = mc[2 * g + half];        // s = 8g + 4*half + 0..3
            const float4 c1 = mc[8 + 2 * g + half];    // + 32
            const float cv0[4] = {c0.x, c0.y, c0.z, c0.w};
            const float cv1[4] = {c1.x, c1.y, c1.z, c1.w};
            float p0[4], p1[4];
#pragma unroll
            for (int jl = 0; jl < 4; jl++) {
                const int r = 4 * g + jl;
                p0[jl] = __expf(st0[r] + cv0[jl]);
                p1[jl] = __expf(st1[r] + cv1[jl]);
            }
            ls[g]     += (p0[0] + p0[1]) + (p0[2] + p0[3]);
            ls[4 + g] += (p1[0] + p1[1]) + (p1[2] + p1[3]);
            dw[g][0] = cvt_pk_bf16(p0[0], p0[1]);
            dw[g][1] = cvt_pk_bf16(p0[2], p0[3]);
            dw[4 + g][0] = cvt_pk_bf16(p1[0], p1[1]);
            dw[4 + g][1] = cvt_pk_bf16(p1[2], p1[3]);
        }
        // permlane32_swap: frag f (s-chunk 16f..16f+15), word t from h'=0, word 2+t from h'=1
        Frag pa[4];
#pragma unroll
        for (int f = 0; f < 4; f++)
#pragma unroll
            for (int t = 0; t < 2; t++) {
                unsigned a = dw[2 * f][t], bq = dw[2 * f + 1][t];
                pl32swap(a, bq);
                pa[f].u[t] = a;
                pa[f].u[2 + t] = bq;
            }
        // PV: 4 s-chunks x 4 dv-blocks
#pragma unroll
        for (int f = 0; f < 4; f++)
#pragma unroll
            for (int nt = 0; nt < 4; nt++) {
                bf16x8 vf = *(const bf16x8*)&Vb[cur][(nt * 32 + l31) * 64 +
                                                     (((2 * f + half) ^ (l31 & 7)) * 8)];
                oacc[nt] = __builtin_amdgcn_mfma_f32_32x32x16_bf16(pa[f].v, vf, oacc[nt], 0, 0, 0);
            }
        __syncthreads();  // publishes buf[nxt]; prefetch had the whole iter to land
    }

    // denominator: lanes (l31, h) + (l31, h^1) together hold the full row sum
    float lsum = ((ls[0] + ls[1]) + (ls[2] + ls[3])) + ((ls[4] + ls[5]) + (ls[6] + ls[7]));
    lsum += __shfl_xor(lsum, 32, 64);
    const float invq = 1.0f / lsum;            // denom for q = l31
    float invv[16];
#pragma unroll
    for (int r = 0; r < 16; r++)
        invv[r] = __shfl(invq, (r & 3) + 8 * (r >> 2) + 4 * half, 64);
#pragma unroll
    for (int nt = 0; nt < 4; nt++)
#pragma unroll
        for (int r = 0; r < 16; r++) {
            const int row = (r & 3) + 8 * (r >> 2) + 4 * half;
            O[baseQ + (long)(q0 + row) * DMODEL + nt * 32 + l31] = f2bf(oacc[nt][r] * invv[r]);
        }
}

// ------------- residual + layernorm: out = LN(a + b) * g + be -------------
__global__ __launch_bounds__(256) void ln_kernel(const float* __restrict__ a,
                                                 const float* __restrict__ b,
                                                 const float* __restrict__ gamma,
                                                 const float* __restrict__ beta, int gi,
                                                 float* __restrict__ out_f,
                                                 u16* __restrict__ out_bf) {
    __shared__ float red[8];
    const int row = blockIdx.x;
    const int tid = threadIdx.x;
    const long off = (long)row * DMODEL + tid * 4;
    float4 va = *(const float4*)&a[off];
    float4 vb = *(const float4*)&b[off];
    float4 v;
    v.x = va.x + vb.x; v.y = va.y + vb.y; v.z = va.z + vb.z; v.w = va.w + vb.w;
    float s = v.x + v.y + v.z + v.w;
    float sq = v.x * v.x + v.y * v.y + v.z * v.z + v.w * v.w;
    for (int d = 1; d < 64; d <<= 1) {
        s += __shfl_xor(s, d, 64);
        sq += __shfl_xor(sq, d, 64);
    }
    int wave = tid >> 6;
    if ((tid & 63) == 0) { red[wave * 2] = s; red[wave * 2 + 1] = sq; }
    __syncthreads();
    s = red[0] + red[2] + red[4] + red[6];
    sq = red[1] + red[3] + red[5] + red[7];
    float mean = s * (1.0f / DMODEL);
    float var = sq * (1.0f / DMODEL) - mean * mean;
    float rstd = rsqrtf(var + 1e-14f);
    float g = gamma[gi], be = beta[gi];
    float4 o;
    o.x = (v.x - mean) * rstd * g + be;
    o.y = (v.y - mean) * rstd * g + be;
    o.z = (v.z - mean) * rstd * g + be;
    o.w = (v.w - mean) * rstd * g + be;
    *(float4*)&out_f[off] = o;
    if (out_bf) {
        uint2 ob;
        ob.x = (unsigned)f2bf(o.x) | ((unsigned)f2bf(o.y) << 16);
        ob.y = (unsigned)f2bf(o.z) | ((unsigned)f2bf(o.w) << 16);
        *(uint2*)&out_bf[off] = ob;
    }
}

extern "C" void kernel_launch(void* const* d_in, const int* in_sizes, int n_in,
                              void* d_out, int out_size, void* d_ws, size_t ws_size,
                              hipStream_t stream) {
    const float* query = (const float*)d_in[0];
    const float* key   = (const float*)d_in[1];
    const float* value = (const float*)d_in[2];
    const float* mask  = (const float*)d_in[3];
    const float* Wq = (const float*)d_in[4];
    const float* Wk = (const float*)d_in[5];
    const float* Wv = (const float*)d_in[6];
    const float* Wo = (const float*)d_in[7];
    const float* W1 = (const float*)d_in[8];
    const float* b1 = (const float*)d_in[9];
    const float* W2 = (const float*)d_in[10];
    const float* b2 = (const float*)d_in[11];
    const float* gamma = (const float*)d_in[12];
    const float* beta  = (const float*)d_in[13];

    char* ws = (char*)d_ws;
    const size_t MB = 1024 * 1024;
    u16* WqT = (u16*)(ws + 0 * MB);    // 2 MB  (H*DK, D)
    u16* WkT = (u16*)(ws + 2 * MB);    // 2 MB
    u16* WvT = (u16*)(ws + 4 * MB);    // 2 MB
    u16* WoT = (u16*)(ws + 6 * MB);    // 2 MB  (D, H*DV)
    u16* W1T = (u16*)(ws + 8 * MB);    // 4 MB  (DFF, D)
    u16* W2T = (u16*)(ws + 12 * MB);   // 4 MB  (D, DFF)
    u16* qbf = (u16*)(ws + 16 * MB);   // 16 MB   (later reused as x_bf)
    u16* kbf = (u16*)(ws + 32 * MB);   // 16 MB   (kbf+vbf later reused as h1, 32 MB)
    u16* vbf = (u16*)(ws + 48 * MB);   // 16 MB
    u16* Qp  = (u16*)(ws + 64 * MB);   // 16 MB
    u16* Kp  = (u16*)(ws + 80 * MB);   // 16 MB
    u16* VtP = (u16*)(ws + 96 * MB);   // 16 MB  Vt[b][h][dv][s]
    u16* Op  = (u16*)(ws + 112 * MB);  // 16 MB
    float* proj = (float*)(ws + 128 * MB);  // 32 MB (later reused as FFN out)
    float* xf   = (float*)(ws + 160 * MB);  // 32 MB
    u16* xbf = qbf;
    u16* h1  = kbf;

    // ---- weight packing (tiled transpose + bf16, coalesced both sides) ----
    transpose_qkv_w<<<dim3(4, 32, 24), 256, 0, stream>>>(Wq, Wk, Wv, WqT, WkT, WvT);
    transpose_bf_tiled<<<dim3(32, 32, 1), 256, 0, stream>>>(Wo, WoT, 1024, 1024);
    transpose_bf_tiled<<<dim3(64, 32, 1), 256, 0, stream>>>(W1, W1T, 1024, 2048);
    transpose_bf_tiled<<<dim3(32, 64, 1), 256, 0, stream>>>(W2, W2T, 2048, 1024);

    // ---- activation conversion (fused q,k,v) ----
    const int n4 = BROWS * DMODEL / 4;
    convert3_kernel<<<dim3(n4 / 256, 3), 256, 0, stream>>>(query, key, value, qbf, kbf, vbf, n4);

    // ---- QKV projections, one batched launch (z=0:Q, 1:K, 2:V->transposed) ----
    gemm_qkv_kernel<<<dim3(64, 8, 3), 256, 0, stream>>>(qbf, kbf, vbf, WqT, WkT, WvT,
                                                        Qp, Kp, VtP);

    // ---- attention (512 blocks, XCD-swizzled decode inside) ----
    attn_kernel<<<dim3(512, 1, 1), 256, 0, stream>>>(Qp, Kp, VtP, mask, Op);

    // ---- output projection ----
    gemm_bt_kernel<0><<<dim3(64, 8), 256, 0, stream>>>(Op, WoT, nullptr, proj, 1024, 1024);

    // ---- LN1: x = LN(value + proj) ----
    ln_kernel<<<dim3(BROWS), 256, 0, stream>>>(value, proj, gamma, beta, 0, xf, xbf);

    // ---- FFN ----
    gemm_bt_kernel<2><<<dim3(64, 16), 256, 0, stream>>>(xbf, W1T, b1, h1, 2048, 1024);
    gemm_bt_kernel<3><<<dim3(64, 8), 256, 0, stream>>>(h1, W2T, b2, proj, 1024, 2048);

    // ---- LN2: out = LN(x + ffn) ----
    ln_kernel<<<dim3(BROWS), 256, 0, stream>>>(xf, proj, gamma, beta, 1, (float*)d_out, nullptr);
}

// Round 11
// 457.763 us; speedup vs baseline: 1.1163x; 1.0919x over previous
//
#include <hip/hip_runtime.h>

#define S_LEN 2048
#define DMODEL 1024
#define NHEAD 8
#define DHEAD 128
#define DFF_N 2048
#define BROWS 8192   // B * S

typedef unsigned short u16;
typedef __attribute__((ext_vector_type(8))) short bf16x8;
typedef __attribute__((ext_vector_type(4))) float f32x4;
typedef __attribute__((ext_vector_type(16))) float f32x16;

__device__ __forceinline__ u16 f2bf(float f) {
    union { float f; unsigned int u; } v; v.f = f;
    unsigned int u = v.u;
    unsigned int r = (u + 0x7FFFu + ((u >> 16) & 1u)) >> 16;
    return (u16)r;
}

__device__ __forceinline__ float bf2f(unsigned h) {
    union { unsigned u; float f; } v; v.u = h << 16; return v.f;
}

__device__ __forceinline__ void async_copy16(const u16* g, u16* l) {
    __builtin_amdgcn_global_load_lds((const __attribute__((address_space(1))) void*)g,
                                     (__attribute__((address_space(3))) void*)l, 16, 0, 0);
}

union Frag { bf16x8 v; unsigned u[4]; };

__device__ __forceinline__ unsigned cvt_pk_bf16(float a, float b) {
    unsigned d;
    asm("v_cvt_pk_bf16_f32 %0, %1, %2" : "=v"(d) : "v"(a), "v"(b));
    return d;  // lo = bf16(a), hi = bf16(b)
}

// swaps hi32 lanes of a with lo32 lanes of b (gfx950)
__device__ __forceinline__ void pl32swap(unsigned& a, unsigned& b) {
    asm("v_permlane32_swap_b32 %0, %1" : "+v"(a), "+v"(b));
}

// ---------------- fused convert f32 -> bf16 for q,k,v ----------------
__global__ __launch_bounds__(256) void convert3_kernel(const float* __restrict__ a,
                                                       const float* __restrict__ b,
                                                       const float* __restrict__ c,
                                                       u16* __restrict__ oa,
                                                       u16* __restrict__ ob,
                                                       u16* __restrict__ oc, int n4) {
    const float* src = (blockIdx.y == 0) ? a : (blockIdx.y == 1) ? b : c;
    u16* dst = (blockIdx.y == 0) ? oa : (blockIdx.y == 1) ? ob : oc;
    int i = blockIdx.x * 256 + threadIdx.x;
    if (i < n4) {
        float4 v = ((const float4*)src)[i];
        uint2 o;
        o.x = (unsigned)f2bf(v.x) | ((unsigned)f2bf(v.y) << 16);
        o.y = (unsigned)f2bf(v.z) | ((unsigned)f2bf(v.w) << 16);
        ((uint2*)dst)[i] = o;
    }
}

// ---- tiled transpose + convert: out[b][c][r] = in[b][r][c], coalesced ----
__global__ __launch_bounds__(256) void transpose_bf_tiled(const float* __restrict__ in,
                                                          u16* __restrict__ out,
                                                          int R, int C) {
    __shared__ float T[32][33];
    const long bo = (long)blockIdx.z * R * C;
    const int r0 = blockIdx.y * 32, c0 = blockIdx.x * 32;
    const int tx = threadIdx.x & 31, ty = threadIdx.x >> 5;  // ty 0..7
    for (int k = 0; k < 4; k++)
        T[ty + 8 * k][tx] = in[bo + (long)(r0 + ty + 8 * k) * C + c0 + tx];
    __syncthreads();
    for (int k = 0; k < 4; k++)
        out[bo + (long)(c0 + ty + 8 * k) * R + r0 + tx] = f2bf(T[tx][ty + 8 * k]);
}

// ---- batched transpose for the three (8,1024,128) QKV weights ----
__global__ __launch_bounds__(256) void transpose_qkv_w(const float* __restrict__ Wq,
                                                       const float* __restrict__ Wk,
                                                       const float* __restrict__ Wv,
                                                       u16* __restrict__ WqT,
                                                       u16* __restrict__ WkT,
                                                       u16* __restrict__ WvT) {
    __shared__ float T[32][33];
    const int w = blockIdx.z >> 3, bz = blockIdx.z & 7;
    const float* in = (w == 0) ? Wq : (w == 1) ? Wk : Wv;
    u16* out = (w == 0) ? WqT : (w == 1) ? WkT : WvT;
    const long bo = (long)bz * 1024 * 128;
    const int r0 = blockIdx.y * 32, c0 = blockIdx.x * 32;
    const int tx = threadIdx.x & 31, ty = threadIdx.x >> 5;
    for (int k = 0; k < 4; k++)
        T[ty + 8 * k][tx] = in[bo + (long)(r0 + ty + 8 * k) * 128 + c0 + tx];
    __syncthreads();
    for (int k = 0; k < 4; k++)
        out[bo + (long)(c0 + ty + 8 * k) * 1024 + r0 + tx] = f2bf(T[tx][ty + 8 * k]);
}

// -------- shared GEMM main loop: async LDS double-buffer, 1 barrier/iter --------
__device__ __forceinline__ void gemm_core(const u16* __restrict__ A,
                                          const u16* __restrict__ Bt, int K,
                                          long row0, long col0, u16* As, u16* Bs,
                                          f32x4 (*acc)[4]) {
    const int tid = threadIdx.x;
    const int lane = tid & 63, wave = tid >> 6;
    const int l15 = lane & 15, quad = lane >> 4;
    const int wx = wave & 1, wy = wave >> 1;
    const int srow = wave * 16 + (lane >> 2);
    const int scol = (lane & 3) * 8;
    const u16* ag0 = &A[(row0 + srow) * K + scol];
    const u16* ag1 = &A[(row0 + 64 + srow) * K + scol];
    const u16* bg0 = &Bt[(col0 + srow) * K + scol];
    const u16* bg1 = &Bt[(col0 + 64 + srow) * K + scol];
    const int l0 = (wave * 16) * 32;
    const int l1 = (64 + wave * 16) * 32;
    const int BUF = 128 * 32;

    async_copy16(ag0, &As[l0]);
    async_copy16(ag1, &As[l1]);
    async_copy16(bg0, &Bs[l0]);
    async_copy16(bg1, &Bs[l1]);
    __syncthreads();

    const int nk = K >> 5;
    for (int kt = 0; kt < nk; kt++) {
        const int cur = (kt & 1) * BUF;
        const int nxt = BUF - cur;
        if (kt + 1 < nk) {
            const int k0 = (kt + 1) * 32;
            async_copy16(ag0 + k0, &As[nxt + l0]);
            async_copy16(ag1 + k0, &As[nxt + l1]);
            async_copy16(bg0 + k0, &Bs[nxt + l0]);
            async_copy16(bg1 + k0, &Bs[nxt + l1]);
        }
        bf16x8 af[4], bfr[4];
        for (int mi = 0; mi < 4; mi++)
            af[mi] = *(const bf16x8*)&As[cur + (wy * 64 + mi * 16 + l15) * 32 + quad * 8];
        for (int ni = 0; ni < 4; ni++)
            bfr[ni] = *(const bf16x8*)&Bs[cur + (wx * 64 + ni * 16 + l15) * 32 + quad * 8];
        for (int mi = 0; mi < 4; mi++)
            for (int ni = 0; ni < 4; ni++)
                acc[mi][ni] = __builtin_amdgcn_mfma_f32_16x16x32_bf16(af[mi], bfr[ni],
                                                                      acc[mi][ni], 0, 0, 0);
        __syncthreads();
    }
}

// NOTE (R9 lesson): NO XCD swizzle here. For grids with gridDim.x = 64 (all ours),
// the DEFAULT round-robin dispatch already places the 8-16 blocks sharing an
// A-row-panel on the same XCD (64 = 0 mod 8), giving a ~4 MB L2 working set.
// The R9 col-banded swizzle broke this: FETCH_SIZE 54 -> 200 MB on qkv.

// ---------------- GEMM: C[M x N] = A[M x K] @ Bt[N x K]^T ----------------
// EPI: 0 = f32 out; 1 = bf16 out; 2 = bias+relu, bf16 out; 3 = bias, f32 out;
//      4 = bias, bf16 out
template <int EPI>
__global__ __launch_bounds__(256) void gemm_bt_kernel(const u16* __restrict__ A,
                                                      const u16* __restrict__ Bt,
                                                      const float* __restrict__ bias,
                                                      void* __restrict__ Cp,
                                                      int N, int K) {
    __shared__ u16 As[2 * 128 * 32];
    __shared__ u16 Bs[2 * 128 * 32];
    const int tid = threadIdx.x;
    const int lane = tid & 63, wave = tid >> 6;
    const int l15 = lane & 15, quad = lane >> 4;
    const int wx = wave & 1, wy = wave >> 1;
    const long row0 = (long)blockIdx.x * 128;
    const long col0 = (long)blockIdx.y * 128;

    f32x4 acc[4][4];
    for (int i = 0; i < 4; i++)
        for (int j = 0; j < 4; j++) acc[i][j] = (f32x4){0.f, 0.f, 0.f, 0.f};

    gemm_core(A, Bt, K, row0, col0, As, Bs, acc);

    for (int mi = 0; mi < 4; mi++)
        for (int ni = 0; ni < 4; ni++) {
            const long col = col0 + wx * 64 + ni * 16 + l15;
            float bv = (EPI == 2 || EPI == 3 || EPI == 4) ? bias[col] : 0.0f;
            for (int r = 0; r < 4; r++) {
                const long row = row0 + wy * 64 + mi * 16 + quad * 4 + r;
                float v = acc[mi][ni][r] + bv;
                if (EPI == 2) v = fmaxf(v, 0.0f);
                if (EPI == 0 || EPI == 3)
                    ((float*)Cp)[row * N + col] = v;
                else
                    ((u16*)Cp)[row * N + col] = f2bf(v);
            }
        }
}

// ---- batched QKV GEMM: z selects (A, Bt, epilogue); N=K=1024 ----
__global__ __launch_bounds__(256) void gemm_qkv_kernel(const u16* __restrict__ A0,
                                                       const u16* __restrict__ A1,
                                                       const u16* __restrict__ A2,
                                                       const u16* __restrict__ B0,
                                                       const u16* __restrict__ B1,
                                                       const u16* __restrict__ B2,
                                                       u16* __restrict__ Qp,
                                                       u16* __restrict__ Kp,
                                                       u16* __restrict__ Vtp) {
    __shared__ u16 As[2 * 128 * 32];
    __shared__ u16 Bs[2 * 128 * 32];
    const int z = blockIdx.z;
    const u16* A = (z == 0) ? A0 : (z == 1) ? A1 : A2;
    const u16* Bt = (z == 0) ? B0 : (z == 1) ? B1 : B2;
    const int tid = threadIdx.x;
    const int lane = tid & 63, wave = tid >> 6;
    const int l15 = lane & 15, quad = lane >> 4;
    const int wx = wave & 1, wy = wave >> 1;
    const long row0 = (long)blockIdx.x * 128;
    const long col0 = (long)blockIdx.y * 128;

    f32x4 acc[4][4];
    for (int i = 0; i < 4; i++)
        for (int j = 0; j < 4; j++) acc[i][j] = (f32x4){0.f, 0.f, 0.f, 0.f};

    gemm_core(A, Bt, 1024, row0, col0, As, Bs, acc);

    if (z == 2) {
        // transposed bf16 store: Vt[((b*8+h)*128+dv)*2048 + s]
        for (int mi = 0; mi < 4; mi++)
            for (int ni = 0; ni < 4; ni++) {
                const int row = (int)row0 + wy * 64 + mi * 16 + quad * 4;  // = b*2048 + s
                const int col = (int)col0 + wx * 64 + ni * 16 + l15;       // = h*128 + dv
                const int bb = row >> 11, s = row & 2047;
                uint2 o;
                o.x = (unsigned)f2bf(acc[mi][ni][0]) | ((unsigned)f2bf(acc[mi][ni][1]) << 16);
                o.y = (unsigned)f2bf(acc[mi][ni][2]) | ((unsigned)f2bf(acc[mi][ni][3]) << 16);
                *(uint2*)&Vtp[((long)(bb * 1024 + col) << 11) + s] = o;
            }
    } else {
        u16* Cp = (z == 0) ? Qp : Kp;
        for (int mi = 0; mi < 4; mi++)
            for (int ni = 0; ni < 4; ni++) {
                const long col = col0 + wx * 64 + ni * 16 + l15;
                for (int r = 0; r < 4; r++) {
                    const long row = row0 + wy * 64 + mi * 16 + quad * 4 + r;
                    Cp[row * 1024 + col] = f2bf(acc[mi][ni][r]);
                }
            }
    }
}

// ---------------- Flash attention v4: swapped QK^T, in-register softmax ----------------
// (verified R10: mask addend LDS table + 8-way lsum partials; 87.7 us)
__global__ __launch_bounds__(256, 2) void attn_kernel(const u16* __restrict__ Q,
                                                      const u16* __restrict__ Km,
                                                      const u16* __restrict__ Vt,
                                                      const float* __restrict__ mask,
                                                      u16* __restrict__ O) {
    __shared__ u16 Kb[2][64 * 128];   // [s 0..63][dk, swizzled 16B blocks]
    __shared__ u16 Vb[2][128 * 64];   // [dv 0..127][s, swizzled 16B blocks]
    __shared__ float Mc[S_LEN];       // mask addend table, 8 KB
    const int tid = threadIdx.x;
    const int lane = tid & 63, wave = tid >> 6;
    const int l31 = lane & 31, half = lane >> 5;

    // XCD-aware decode: all 16 q-tiles of a (b,h) share one XCD's L2
    const int linear = blockIdx.x;            // 0..511
    const int xcd = linear & 7, jj = linear >> 3;
    const int bh = xcd * 4 + (jj & 3);        // 4 (b,h) streams per XCD
    const int qt = jj >> 2;                   // 0..15
    const int b = bh >> 3, h = bh & 7;

    const long baseQ = ((long)b * S_LEN) * DMODEL + h * DHEAD;
    const long baseV = ((long)(b * NHEAD + h) * DHEAD) * S_LEN;
    const int q0 = qt * 128 + wave * 32;

    bf16x8 qf[8];
#pragma unroll
    for (int kk = 0; kk < 8; kk++)
        qf[kk] = *(const bf16x8*)&Q[baseQ + (long)(q0 + l31) * DMODEL + kk * 16 + half * 8];

    // staging descriptors: K 16 instrs/tile (4/wave), V 16 instrs/tile (4/wave)
    const int krow = 4 * wave + (lane >> 4);            // j adds 16 rows
    const int kcb = (lane & 15) ^ (krow & 7);
    const u16* gK = Km + baseQ + (long)krow * DMODEL + kcb * 8;
    const int vrow = 8 * wave + (lane >> 3);            // j adds 32 rows
    const int vcb = (lane & 7) ^ (vrow & 7);
    const u16* gV = Vt + baseV + (long)vrow * S_LEN + vcb * 8;
    const int ldo = wave * 512;                         // u16; + j*2048

    f32x16 oacc[4];
#pragma unroll
    for (int i = 0; i < 4; i++)
#pragma unroll
        for (int r = 0; r < 16; r++) oacc[i][r] = 0.f;
    float ls[8];
#pragma unroll
    for (int i = 0; i < 8; i++) ls[i] = 0.f;

    // prologue: mask addend table + stage tile 0 into buffer 0
#pragma unroll
    for (int i = 0; i < S_LEN / 256; i++) {
        const float m = mask[(long)b * S_LEN + i * 256 + tid];
        Mc[i * 256 + tid] = fmaf(m, 1e30f, -1e30f) - 20.0f;
    }
#pragma unroll
    for (int j = 0; j < 4; j++) {
        async_copy16(gK + j * (16 * DMODEL), &Kb[0][ldo + j * 2048]);
        async_copy16(gV + j * (32 * S_LEN), &Vb[0][ldo + j * 2048]);
    }
    __syncthreads();

    const int NT = S_LEN / 64;
    for (int kt = 0; kt < NT; kt++) {
        const int cur = kt & 1, nxt = cur ^ 1;
        if (kt + 1 < NT) {
            const long koff = (long)(kt + 1) * 64 * DMODEL;
            const long voff = (long)(kt + 1) * 64;
#pragma unroll
            for (int j = 0; j < 4; j++) {
                async_copy16(gK + koff + j * (16 * DMODEL), &Kb[nxt][ldo + j * 2048]);
                async_copy16(gV + voff + j * (32 * S_LEN), &Vb[nxt][ldo + j * 2048]);
            }
        }
        const float4* mc = (const float4*)&Mc[kt * 64];

        // QK^T swapped: A = K rows (s), B = Q cols (q) -> P lane-local per q row
        f32x16 st0, st1;
#pragma unroll
        for (int r = 0; r < 16; r++) { st0[r] = 0.f; st1[r] = 0.f; }
#pragma unroll
        for (int kk = 0; kk < 8; kk++) {
            const int cb = ((kk * 2 + half) ^ (l31 & 7)) * 8;
            bf16x8 kf0 = *(const bf16x8*)&Kb[cur][l31 * 128 + cb];
            bf16x8 kf1 = *(const bf16x8*)&Kb[cur][(32 + l31) * 128 + cb];
            st0 = __builtin_amdgcn_mfma_f32_32x32x16_bf16(kf0, qf[kk], st0, 0, 0, 0);
            st1 = __builtin_amdgcn_mfma_f32_32x32x16_bf16(kf1, qf[kk], st1, 0, 0, 0);
        }

        // p = exp(st + c[s]); pack to bf16 dwords per 4-row group
        unsigned dw[8][2];
#pragma unroll
        for (int g = 0; g < 4; g++) {
            const float4 c0 = mc[2 * g + half];        // s = 8g + 4*half + 0..3
            const float4 c1 = mc[8 + 2 * g + half];    // + 32
            const float cv0[4] = {c0.x, c0.y, c0.z, c0.w};
            const float cv1[4] = {c1.x, c1.y, c1.z, c1.w};
            float p0[4], p1[4];
#pragma unroll
            for (int jl = 0; jl < 4; jl++) {
                const int r = 4 * g + jl;
                p0[jl] = __expf(st0[r] + cv0[jl]);
                p1[jl] = __expf(st1[r] + cv1[jl]);
            }
            ls[g]     += (p0[0] + p0[1]) + (p0[2] + p0[3]);
            ls[4 + g] += (p1[0] + p1[1]) + (p1[2] + p1[3]);
            dw[g][0] = cvt_pk_bf16(p0[0], p0[1]);
            dw[g][1] = cvt_pk_bf16(p0[2], p0[3]);
            dw[4 + g][0] = cvt_pk_bf16(p1[0], p1[1]);
            dw[4 + g][1] = cvt_pk_bf16(p1[2], p1[3]);
        }
        // permlane32_swap: frag f (s-chunk 16f..16f+15), word t from h'=0, word 2+t from h'=1
        Frag pa[4];
#pragma unroll
        for (int f = 0; f < 4; f++)
#pragma unroll
            for (int t = 0; t < 2; t++) {
                unsigned a = dw[2 * f][t], bq = dw[2 * f + 1][t];
                pl32swap(a, bq);
                pa[f].u[t] = a;
                pa[f].u[2 + t] = bq;
            }
        // PV: 4 s-chunks x 4 dv-blocks
#pragma unroll
        for (int f = 0; f < 4; f++)
#pragma unroll
            for (int nt = 0; nt < 4; nt++) {
                bf16x8 vf = *(const bf16x8*)&Vb[cur][(nt * 32 + l31) * 64 +
                                                     (((2 * f + half) ^ (l31 & 7)) * 8)];
                oacc[nt] = __builtin_amdgcn_mfma_f32_32x32x16_bf16(pa[f].v, vf, oacc[nt], 0, 0, 0);
            }
        __syncthreads();  // publishes buf[nxt]; prefetch had the whole iter to land
    }

    // denominator: lanes (l31, h) + (l31, h^1) together hold the full row sum
    float lsum = ((ls[0] + ls[1]) + (ls[2] + ls[3])) + ((ls[4] + ls[5]) + (ls[6] + ls[7]));
    lsum += __shfl_xor(lsum, 32, 64);
    const float invq = 1.0f / lsum;            // denom for q = l31
    float invv[16];
#pragma unroll
    for (int r = 0; r < 16; r++)
        invv[r] = __shfl(invq, (r & 3) + 8 * (r >> 2) + 4 * half, 64);
#pragma unroll
    for (int nt = 0; nt < 4; nt++)
#pragma unroll
        for (int r = 0; r < 16; r++) {
            const int row = (r & 3) + 8 * (r >> 2) + 4 * half;
            O[baseQ + (long)(q0 + row) * DMODEL + nt * 32 + l31] = f2bf(oacc[nt][r] * invv[r]);
        }
}

// ------------- residual + layernorm: out = LN(a + b) * g + be -------------
// A_BF: a is bf16 (else f32). b is always bf16. OUT_F: write f32 out_f (else bf16 out_bf).
template <int A_BF, int OUT_F>
__global__ __launch_bounds__(256) void ln_kernel(const void* __restrict__ a,
                                                 const u16* __restrict__ b,
                                                 const float* __restrict__ gamma,
                                                 const float* __restrict__ beta, int gi,
                                                 float* __restrict__ out_f,
                                                 u16* __restrict__ out_bf) {
    __shared__ float red[8];
    const int row = blockIdx.x;
    const int tid = threadIdx.x;
    const long off = (long)row * DMODEL + tid * 4;
    float4 va;
    if (A_BF) {
        uint2 ua = *(const uint2*)((const u16*)a + off);
        va.x = bf2f(ua.x & 0xffffu); va.y = bf2f(ua.x >> 16);
        va.z = bf2f(ua.y & 0xffffu); va.w = bf2f(ua.y >> 16);
    } else {
        va = *(const float4*)((const float*)a + off);
    }
    uint2 ub = *(const uint2*)&b[off];
    float4 vb;
    vb.x = bf2f(ub.x & 0xffffu); vb.y = bf2f(ub.x >> 16);
    vb.z = bf2f(ub.y & 0xffffu); vb.w = bf2f(ub.y >> 16);
    float4 v;
    v.x = va.x + vb.x; v.y = va.y + vb.y; v.z = va.z + vb.z; v.w = va.w + vb.w;
    float s = v.x + v.y + v.z + v.w;
    float sq = v.x * v.x + v.y * v.y + v.z * v.z + v.w * v.w;
    for (int d = 1; d < 64; d <<= 1) {
        s += __shfl_xor(s, d, 64);
        sq += __shfl_xor(sq, d, 64);
    }
    int wave = tid >> 6;
    if ((tid & 63) == 0) { red[wave * 2] = s; red[wave * 2 + 1] = sq; }
    __syncthreads();
    s = red[0] + red[2] + red[4] + red[6];
    sq = red[1] + red[3] + red[5] + red[7];
    float mean = s * (1.0f / DMODEL);
    float var = sq * (1.0f / DMODEL) - mean * mean;
    float rstd = rsqrtf(var + 1e-14f);
    float g = gamma[gi], be = beta[gi];
    float4 o;
    o.x = (v.x - mean) * rstd * g + be;
    o.y = (v.y - mean) * rstd * g + be;
    o.z = (v.z - mean) * rstd * g + be;
    o.w = (v.w - mean) * rstd * g + be;
    if (OUT_F) {
        *(float4*)&out_f[off] = o;
    } else {
        uint2 ob;
        ob.x = (unsigned)f2bf(o.x) | ((unsigned)f2bf(o.y) << 16);
        ob.y = (unsigned)f2bf(o.z) | ((unsigned)f2bf(o.w) << 16);
        *(uint2*)&out_bf[off] = ob;
    }
}

extern "C" void kernel_launch(void* const* d_in, const int* in_sizes, int n_in,
                              void* d_out, int out_size, void* d_ws, size_t ws_size,
                              hipStream_t stream) {
    const float* query = (const float*)d_in[0];
    const float* key   = (const float*)d_in[1];
    const float* value = (const float*)d_in[2];
    const float* mask  = (const float*)d_in[3];
    const float* Wq = (const float*)d_in[4];
    const float* Wk = (const float*)d_in[5];
    const float* Wv = (const float*)d_in[6];
    const float* Wo = (const float*)d_in[7];
    const float* W1 = (const float*)d_in[8];
    const float* b1 = (const float*)d_in[9];
    const float* W2 = (const float*)d_in[10];
    const float* b2 = (const float*)d_in[11];
    const float* gamma = (const float*)d_in[12];
    const float* beta  = (const float*)d_in[13];

    char* ws = (char*)d_ws;
    const size_t MB = 1024 * 1024;
    u16* WqT = (u16*)(ws + 0 * MB);    // 2 MB  (H*DK, D)
    u16* WkT = (u16*)(ws + 2 * MB);    // 2 MB
    u16* WvT = (u16*)(ws + 4 * MB);    // 2 MB
    u16* WoT = (u16*)(ws + 6 * MB);    // 2 MB  (D, H*DV)
    u16* W1T = (u16*)(ws + 8 * MB);    // 4 MB  (DFF, D)
    u16* W2T = (u16*)(ws + 12 * MB);   // 4 MB  (D, DFF)
    u16* qbf = (u16*)(ws + 16 * MB);   // 16 MB   (later reused as x_bf)
    u16* kbf = (u16*)(ws + 32 * MB);   // 16 MB   (kbf+vbf later reused as h1, 32 MB)
    u16* vbf = (u16*)(ws + 48 * MB);   // 16 MB
    u16* Qp  = (u16*)(ws + 64 * MB);   // 16 MB
    u16* Kp  = (u16*)(ws + 80 * MB);   // 16 MB
    u16* VtP = (u16*)(ws + 96 * MB);   // 16 MB  Vt[b][h][dv][s]
    u16* Op  = (u16*)(ws + 112 * MB);  // 16 MB
    u16* projbf = (u16*)(ws + 128 * MB);  // 16 MB (Wo out; reused for FFN2 out)
    u16* xbf = qbf;
    u16* h1  = kbf;

    // ---- weight packing (tiled transpose + bf16, coalesced both sides) ----
    transpose_qkv_w<<<dim3(4, 32, 24), 256, 0, stream>>>(Wq, Wk, Wv, WqT, WkT, WvT);
    transpose_bf_tiled<<<dim3(32, 32, 1), 256, 0, stream>>>(Wo, WoT, 1024, 1024);
    transpose_bf_tiled<<<dim3(64, 32, 1), 256, 0, stream>>>(W1, W1T, 1024, 2048);
    transpose_bf_tiled<<<dim3(32, 64, 1), 256, 0, stream>>>(W2, W2T, 2048, 1024);

    // ---- activation conversion (fused q,k,v) ----
    const int n4 = BROWS * DMODEL / 4;
    convert3_kernel<<<dim3(n4 / 256, 3), 256, 0, stream>>>(query, key, value, qbf, kbf, vbf, n4);

    // ---- QKV projections, one batched launch (z=0:Q, 1:K, 2:V->transposed) ----
    gemm_qkv_kernel<<<dim3(64, 8, 3), 256, 0, stream>>>(qbf, kbf, vbf, WqT, WkT, WvT,
                                                        Qp, Kp, VtP);

    // ---- attention (512 blocks, XCD-swizzled decode inside) ----
    attn_kernel<<<dim3(512, 1, 1), 256, 0, stream>>>(Qp, Kp, VtP, mask, Op);

    // ---- output projection (bf16 out: LN1 re-reads it once) ----
    gemm_bt_kernel<1><<<dim3(64, 8), 256, 0, stream>>>(Op, WoT, nullptr, projbf, 1024, 1024);

    // ---- LN1: xbf = LN(value + proj), bf16 only (FFN1 and LN2 both consume bf16) ----
    ln_kernel<0, 0><<<dim3(BROWS), 256, 0, stream>>>(value, projbf, gamma, beta, 0,
                                                     nullptr, xbf);

    // ---- FFN ----
    gemm_bt_kernel<2><<<dim3(64, 16), 256, 0, stream>>>(xbf, W1T, b1, h1, 2048, 1024);
    gemm_bt_kernel<4><<<dim3(64, 8), 256, 0, stream>>>(h1, W2T, b2, projbf, 1024, 2048);

    // ---- LN2: out = LN(x + ffn), f32 final output ----
    ln_kernel<1, 1><<<dim3(BROWS), 256, 0, stream>>>(xbf, projbf, gamma, beta, 1,
                                                     (float*)d_out, nullptr);
}